// Round 3
// baseline (558.745 us; speedup 1.0000x reference)
//
#include <hip/hip_runtime.h>
#include <hip/hip_bf16.h>

#define T_LEN 1024
#define B_SZ  4096

// DPP controls (gfx9/CDNA). All cross-lane moves below are XOR-type
// permutations (quad_perm xor patterns, row_mirror=^15, row_half_mirror=^7),
// which are self-inverse => immune to read-from/write-to convention mixups.
// The only directional op is row_shr (scan idiom: lane i reads lane i-n,
// per LLVM AMDGPUAtomicOptimizer::buildScan), guarded explicitly.
#define DPP_QP(a,b,c,d) ((a)|((b)<<2)|((c)<<4)|((d)<<6))
#define DPP_QPX1 DPP_QP(1,0,3,2)   // lane ^ 1 (within quad)
#define DPP_QPX2 DPP_QP(2,3,0,1)   // lane ^ 2
#define DPP_QPX3 DPP_QP(3,2,1,0)   // lane ^ 3
#define DPP_ROW_SHR(n) (0x110|(n))
#define DPP_ROW_MIRROR 0x140       // lane ^ 15 (within 16-lane row)
#define DPP_ROW_HALF_MIRROR 0x141  // lane ^ 7

template <int CTRL>
__device__ __forceinline__ float dppf(float x) {
  return __int_as_float(__builtin_amdgcn_update_dpp(
      0, __float_as_int(x), CTRL, 0xF, 0xF, true));
}

// Lane layout within each 16-lane group (one batch element):
//   lane16 = w*4 + g   (w = wire/hidden 0..3 in bits[3:2],
//                       g = gate 0=f,1=i,2=g,3=o AND x-quarter, bits[1:0])
// qlayer closed form: out_w = prod_{j<=w} cos(theta_j), theta = W.[x,h]+b+phi
__global__ void __launch_bounds__(64, 1) qlstm_65481071402744_kernel(
    const float* __restrict__ x,
    const float* __restrict__ Wf, const float* __restrict__ bfv,
    const float* __restrict__ Wi, const float* __restrict__ biv,
    const float* __restrict__ Wg, const float* __restrict__ bgv,
    const float* __restrict__ Wo, const float* __restrict__ bov,
    const float* __restrict__ rxf, const float* __restrict__ rxi,
    const float* __restrict__ rxg, const float* __restrict__ rxo,
    float* __restrict__ out) {
  const int tid = threadIdx.x;
  const int g = tid & 3;         // gate index AND x-quarter index
  const int w = (tid >> 2) & 3;  // wire index
  const int b = (blockIdx.x << 2) + (tid >> 4);  // batch element

  auto Wsel = [&](int gg) -> const float* {
    return gg == 0 ? Wf : gg == 1 ? Wi : gg == 2 ? Wg : Wo;
  };

  // x-part weights: lane (w,g) computes p[j] = partial of (gate g^j, wire w)
  // over x-quarter [4g, 4g+4). Reduce: z(gate g) = p0 + xor1(p1)+xor2(p2)+xor3(p3),
  // since lane g^k's p[k] covers gate (g^k)^k = g over quarter g^k.
  float Wxp[4][4];
#pragma unroll
  for (int j = 0; j < 4; ++j) {
    const float* Wt = Wsel(g ^ j);
#pragma unroll
    for (int d = 0; d < 4; ++d) Wxp[j][d] = Wt[w * 20 + (g << 2) + d];
  }
  // h-part weights: Whx[k] multiplies h_{w^k}
  const float* Wown = Wsel(g);
  float Whx[4];
#pragma unroll
  for (int k = 0; k < 4; ++k) Whx[k] = Wown[w * 20 + 16 + (w ^ k)];

  const float* bown = g == 0 ? bfv : g == 1 ? biv : g == 2 ? bgv : bov;
  const float* rxown = g == 0 ? rxf : g == 1 ? rxi : g == 2 ? rxg : rxo;
  const float zinit = bown[w] + rxown[w];  // bias + RX phase folded

  constexpr float L2E = 1.4426950408889634f;
  const bool isG = (g == 2);                      // tanh gate
  const float nlscale = isG ? -2.0f * L2E : -L2E; // exp2 scale
  const float nla = isG ? 2.0f : 1.0f;            // post-rcp fma a
  const float nlb = isG ? -1.0f : 0.0f;           // post-rcp fma b

  float hx = 0.0f, cx = 0.0f;

  // 8-deep register prefetch ring of this lane's x-quarter (covers HBM latency)
  const float4* xp4 = (const float4*)x + ((size_t)b << 2) + g;
  float4 xr[8];
#pragma unroll
  for (int u = 0; u < 8; ++u) xr[u] = xp4[(size_t)u * (B_SZ * 4)];

  float* outp = out + ((size_t)b << 2) + w;

  for (int tb = 0; tb < T_LEN / 8; ++tb) {
#pragma unroll
    for (int u = 0; u < 8; ++u) {
      const int t = (tb << 3) + u;
      const float4 xq = xr[u];
      int tl = t + 8;
      tl = tl < T_LEN ? tl : T_LEN - 1;  // clamped tail prefetch (harmless re-reads)
      xr[u] = xp4[(size_t)tl * (B_SZ * 4)];

      // partial dots over this lane's x-quarter for gates g^j
      float p0 = fmaf(Wxp[0][3], xq.w, fmaf(Wxp[0][2], xq.z, fmaf(Wxp[0][1], xq.y, Wxp[0][0] * xq.x)));
      float p1 = fmaf(Wxp[1][3], xq.w, fmaf(Wxp[1][2], xq.z, fmaf(Wxp[1][1], xq.y, Wxp[1][0] * xq.x)));
      float p2 = fmaf(Wxp[2][3], xq.w, fmaf(Wxp[2][2], xq.z, fmaf(Wxp[2][1], xq.y, Wxp[2][0] * xq.x)));
      float p3 = fmaf(Wxp[3][3], xq.w, fmaf(Wxp[3][2], xq.z, fmaf(Wxp[3][1], xq.y, Wxp[3][0] * xq.x)));

      // xor rotate-reduce within quad: z = sum over all four x-quarters
      float z = (zinit + p0) + dppf<DPP_QPX1>(p1)
              + dppf<DPP_QPX2>(p2) + dppf<DPP_QPX3>(p3);

      // recurrent dot: gather h_{w^1}, h_{w^2}, h_{w^3} via xor compositions
      // (hx is replicated across g within each quad)
      const float hm = dppf<DPP_ROW_MIRROR>(hx);        // hx[lane^15]
      const float h4 = dppf<DPP_QPX3>(dppf<DPP_ROW_HALF_MIRROR>(hx)); // ^7^3 = ^4
      const float h8 = dppf<DPP_ROW_HALF_MIRROR>(hm);   // ^15^7 = ^8
      const float h12 = dppf<DPP_QPX3>(hm);             // ^15^3 = ^12
      z = fmaf(Whx[0], hx, z);
      z = fmaf(Whx[1], h4, z);   // h_{w^1}
      z = fmaf(Whx[2], h8, z);   // h_{w^2}
      z = fmaf(Whx[3], h12, z);  // h_{w^3}

      // c = cos(theta): radians -> revolutions -> fract -> v_cos
      const float c = __builtin_amdgcn_cosf(
          __builtin_amdgcn_fractf(z * 0.15915494309189535f));

      // inclusive cumprod over w (same gate): Hillis-Steele with row_shr:4/:8
      float q = c;
      const float s1 = dppf<DPP_ROW_SHR(4)>(q);   // from wire w-1
      q = (w >= 1) ? q * s1 : q;
      const float s2 = dppf<DPP_ROW_SHR(8)>(q);   // from wire w-2
      q = (w >= 2) ? q * s2 : q;

      // sigmoid (f,i,o) / tanh (g) via exp2+rcp, branch-free per-lane consts
      const float ee = __builtin_amdgcn_exp2f(q * nlscale);
      const float rr = __builtin_amdgcn_rcpf(1.0f + ee);
      const float s = fmaf(rr, nla, nlb);

      // gate all-gather within quad: r[k] = value of gate g^k
      const float r1 = dppf<DPP_QPX1>(s);
      const float r2 = dppf<DPP_QPX2>(s);
      const float r3 = dppf<DPP_QPX3>(s);
      // value of gate G at this lane = r[G ^ g]
      const int k0 = g, k1 = 1 ^ g, k2 = 2 ^ g, k3 = 3 ^ g;
      const float fv = k0 == 0 ? s : k0 == 1 ? r1 : k0 == 2 ? r2 : r3;
      const float iv = k1 == 0 ? s : k1 == 1 ? r1 : k1 == 2 ? r2 : r3;
      const float Gv = k2 == 0 ? s : k2 == 1 ? r1 : k2 == 2 ? r2 : r3;
      const float ov = k3 == 0 ? s : k3 == 1 ? r1 : k3 == 2 ? r2 : r3;

      cx = fmaf(fv, cx, iv * Gv);
      const float e3 = __builtin_amdgcn_exp2f(cx * (-2.0f * L2E));
      const float r4 = __builtin_amdgcn_rcpf(1.0f + e3);
      const float th = fmaf(2.0f, r4, -1.0f);  // tanh(cx)
      hx = ov * th;

      // fp32 output: reference's output dtype is float32 (inputs.dtype)
      if (g == 0) outp[(size_t)t * (B_SZ * 4)] = hx;
    }
  }

  if (g == 0) {
    const size_t base = (size_t)T_LEN * B_SZ * 4;
    out[base + (b << 2) + w] = hx;               // final hx
    out[base + B_SZ * 4 + (b << 2) + w] = cx;    // final cx
  }
}

extern "C" void kernel_launch(void* const* d_in, const int* in_sizes, int n_in,
                              void* d_out, int out_size, void* d_ws, size_t ws_size,
                              hipStream_t stream) {
  const float* x   = (const float*)d_in[0];
  const float* Wf  = (const float*)d_in[1];
  const float* bf_ = (const float*)d_in[2];
  const float* Wi  = (const float*)d_in[3];
  const float* bi_ = (const float*)d_in[4];
  const float* Wg  = (const float*)d_in[5];
  const float* bg_ = (const float*)d_in[6];
  const float* Wo  = (const float*)d_in[7];
  const float* bo_ = (const float*)d_in[8];
  const float* rxf = (const float*)d_in[9];
  const float* rxi = (const float*)d_in[10];
  const float* rxg = (const float*)d_in[11];
  const float* rxo = (const float*)d_in[12];

  // 4096 batch elements * 16 lanes = 65536 threads = 1024 single-wave blocks
  qlstm_65481071402744_kernel<<<(B_SZ * 16) / 64, 64, 0, stream>>>(
      x, Wf, bf_, Wi, bi_, Wg, bg_, Wo, bo_, rxf, rxi, rxg, rxo,
      (float*)d_out);
}

// Round 4
// 517.561 us; speedup vs baseline: 1.0796x; 1.0796x over previous
//
#include <hip/hip_runtime.h>

#define T_LEN 1024
#define B_SZ  4096

// DPP controls (gfx9/CDNA).
// quad_perm xor patterns + broadcasts are direction-unambiguous.
// row_ror convention VERIFIED BY EVIDENCE (round 1 vs round 2 identical
// trajectories): ror:12 reads lane+4, ror:8 reads lane+8, ror:4 reads lane+12.
// row_shr scan (lane i reads i-n) anchored by LLVM AMDGPUAtomicOptimizer.
#define DPP_QP(a,b,c,d) ((a)|((b)<<2)|((c)<<4)|((d)<<6))
#define DPP_QPX1 DPP_QP(1,0,3,2)   // lane ^ 1 (within quad)
#define DPP_QPX2 DPP_QP(2,3,0,1)   // lane ^ 2
#define DPP_QPX3 DPP_QP(3,2,1,0)   // lane ^ 3
#define DPP_BCAST0 DPP_QP(0,0,0,0) // all quad lanes read quad lane 0
#define DPP_BCAST1 DPP_QP(1,1,1,1)
#define DPP_BCAST2 DPP_QP(2,2,2,2)
#define DPP_BCAST3 DPP_QP(3,3,3,3)
#define DPP_ROW_SHR(n) (0x110|(n))
#define DPP_ROW_ROR(n) (0x120|(n))

template <int CTRL>
__device__ __forceinline__ float dppf(float x) {
  return __int_as_float(__builtin_amdgcn_update_dpp(
      0, __float_as_int(x), CTRL, 0xF, 0xF, true));
}
// Scan helper: invalid source lanes receive identity 1.0f (old operand,
// bound_ctrl=false => keep old). Removes the (w>=k) cndmask guards.
template <int CTRL>
__device__ __forceinline__ float dppf_id1(float x) {
  return __int_as_float(__builtin_amdgcn_update_dpp(
      0x3f800000, __float_as_int(x), CTRL, 0xF, 0xF, false));
}

// Lane layout within each 16-lane group (one batch element):
//   lane16 = w*4 + g   (w = wire/hidden 0..3 bits[3:2],
//                       g = gate 0=f,1=i,2=g,3=o AND x-quarter, bits[1:0])
// qlayer closed form: out_w = prod_{j<=w} cos(theta_j), theta = W.[x,h]+b+phi
__global__ void __launch_bounds__(64, 1) qlstm_65481071402744_kernel(
    const float* __restrict__ x,
    const float* __restrict__ Wf, const float* __restrict__ bfv,
    const float* __restrict__ Wi, const float* __restrict__ biv,
    const float* __restrict__ Wg, const float* __restrict__ bgv,
    const float* __restrict__ Wo, const float* __restrict__ bov,
    const float* __restrict__ rxf, const float* __restrict__ rxi,
    const float* __restrict__ rxg, const float* __restrict__ rxo,
    float* __restrict__ out) {
  const int tid = threadIdx.x;
  const int g = tid & 3;         // gate index AND x-quarter index
  const int w = (tid >> 2) & 3;  // wire index
  const int b = (blockIdx.x << 2) + (tid >> 4);  // batch element

  auto Wsel = [&](int gg) -> const float* {
    return gg == 0 ? Wf : gg == 1 ? Wi : gg == 2 ? Wg : Wo;
  };

  // x-part weights: lane (w,g) computes p[j] = partial of (gate g^j, wire w)
  // over x-quarter [4g, 4g+4). xor-reduce brings all quarters to gate g's lane.
  float Wxp[4][4];
#pragma unroll
  for (int j = 0; j < 4; ++j) {
    const float* Wt = Wsel(g ^ j);
#pragma unroll
    for (int d = 0; d < 4; ++d) Wxp[j][d] = Wt[w * 20 + (g << 2) + d];
  }
  // h-part weights for rotate-gather: Whp[k] multiplies h_{(w+k)%4}
  const float* Wown = Wsel(g);
  float Whp[4];
#pragma unroll
  for (int k = 0; k < 4; ++k) Whp[k] = Wown[w * 20 + 16 + ((w + k) & 3)];

  const float* bown = g == 0 ? bfv : g == 1 ? biv : g == 2 ? bgv : bov;
  const float* rxown = g == 0 ? rxf : g == 1 ? rxi : g == 2 ? rxg : rxo;
  const float zinit = bown[w] + rxown[w];  // bias + RX phase folded

  constexpr float L2E = 1.4426950408889634f;
  const bool isG = (g == 2);                      // tanh gate
  const float nlscale = isG ? -2.0f * L2E : -L2E; // exp2 scale
  const float nla = isG ? 2.0f : 1.0f;            // post-rcp fma a
  const float nlb = isG ? -1.0f : 0.0f;           // post-rcp fma b

  float hx = 0.0f, cx = 0.0f;

  // 8-deep register prefetch ring of this lane's x-quarter (covers HBM latency)
  const float4* xp4 = (const float4*)x + ((size_t)b << 2) + g;
  float4 xr[8];
#pragma unroll
  for (int u = 0; u < 8; ++u) xr[u] = xp4[(size_t)u * (B_SZ * 4)];

  float* outp = out + ((size_t)b << 2) + w;

  for (int tb = 0; tb < T_LEN / 8; ++tb) {
    float hb[8];
#pragma unroll
    for (int u = 0; u < 8; ++u) {
      const int t = (tb << 3) + u;
      const float4 xq = xr[u];
      int tl = t + 8;
      tl = tl < T_LEN ? tl : T_LEN - 1;  // clamped tail prefetch
      xr[u] = xp4[(size_t)tl * (B_SZ * 4)];

      // partial dots over this lane's x-quarter for gates g^j (zinit seeded)
      float p0 = fmaf(Wxp[0][0], xq.x, zinit);
      p0 = fmaf(Wxp[0][1], xq.y, p0);
      p0 = fmaf(Wxp[0][2], xq.z, p0);
      p0 = fmaf(Wxp[0][3], xq.w, p0);
      float p1 = fmaf(Wxp[1][3], xq.w, fmaf(Wxp[1][2], xq.z, fmaf(Wxp[1][1], xq.y, Wxp[1][0] * xq.x)));
      float p2 = fmaf(Wxp[2][3], xq.w, fmaf(Wxp[2][2], xq.z, fmaf(Wxp[2][1], xq.y, Wxp[2][0] * xq.x)));
      float p3 = fmaf(Wxp[3][3], xq.w, fmaf(Wxp[3][2], xq.z, fmaf(Wxp[3][1], xq.y, Wxp[3][0] * xq.x)));

      // xor rotate-reduce within quad: zx = full x-dot + bias + phase
      const float zx = (p0 + dppf<DPP_QPX1>(p1)) +
                       (dppf<DPP_QPX2>(p2) + dppf<DPP_QPX3>(p3));

      // recurrent dot: single-hop rotations (independent), depth-3 tree
      const float h1 = dppf<DPP_ROW_ROR(12)>(hx);  // h_{w+1}
      const float h2 = dppf<DPP_ROW_ROR(8)>(hx);   // h_{w+2}
      const float h3 = dppf<DPP_ROW_ROR(4)>(hx);   // h_{w+3}
      float za = fmaf(Whp[0], hx, zx);
      za = fmaf(Whp[1], h1, za);
      const float zb = fmaf(Whp[3], h3, Whp[2] * h2);
      const float z = za + zb;

      // c = cos(theta): radians -> revolutions -> fract -> v_cos
      const float c = __builtin_amdgcn_cosf(
          __builtin_amdgcn_fractf(z * 0.15915494309189535f));

      // inclusive cumprod over w: row_shr scan with identity-1 fill (no guards)
      float q = c * dppf_id1<DPP_ROW_SHR(4)>(c);
      q = q * dppf_id1<DPP_ROW_SHR(8)>(q);

      // sigmoid (f,i,o) / tanh (g) via exp2+rcp, per-lane consts
      const float ee = __builtin_amdgcn_exp2f(q * nlscale);
      const float s = fmaf(__builtin_amdgcn_rcpf(1.0f + ee), nla, nlb);

      // gate all-gather: quad broadcasts (no select tables)
      const float fA = dppf<DPP_BCAST0>(s);
      const float iA = dppf<DPP_BCAST1>(s);
      const float gA = dppf<DPP_BCAST2>(s);
      const float oA = dppf<DPP_BCAST3>(s);

      cx = fmaf(fA, cx, iA * gA);
      const float e3 = __builtin_amdgcn_exp2f(cx * (-2.0f * L2E));
      const float th = fmaf(2.0f, __builtin_amdgcn_rcpf(1.0f + e3), -1.0f);
      hx = oA * th;
      hb[u] = hx;
    }
    // store burst: one exec-mask section per 8 timesteps
    if (g == 0) {
#pragma unroll
      for (int u = 0; u < 8; ++u)
        outp[(size_t)((tb << 3) + u) * (B_SZ * 4)] = hb[u];
    }
  }

  if (g == 0) {
    const size_t base = (size_t)T_LEN * B_SZ * 4;
    out[base + (b << 2) + w] = hx;               // final hx
    out[base + B_SZ * 4 + (b << 2) + w] = cx;    // final cx
  }
}

extern "C" void kernel_launch(void* const* d_in, const int* in_sizes, int n_in,
                              void* d_out, int out_size, void* d_ws, size_t ws_size,
                              hipStream_t stream) {
  const float* x   = (const float*)d_in[0];
  const float* Wf  = (const float*)d_in[1];
  const float* bf_ = (const float*)d_in[2];
  const float* Wi  = (const float*)d_in[3];
  const float* bi_ = (const float*)d_in[4];
  const float* Wg  = (const float*)d_in[5];
  const float* bg_ = (const float*)d_in[6];
  const float* Wo  = (const float*)d_in[7];
  const float* bo_ = (const float*)d_in[8];
  const float* rxf = (const float*)d_in[9];
  const float* rxi = (const float*)d_in[10];
  const float* rxg = (const float*)d_in[11];
  const float* rxo = (const float*)d_in[12];

  // 4096 batch elements * 16 lanes = 65536 threads = 1024 single-wave blocks
  qlstm_65481071402744_kernel<<<(B_SZ * 16) / 64, 64, 0, stream>>>(
      x, Wf, bf_, Wi, bi_, Wg, bg_, Wo, bo_, rxf, rxi, rxg, rxo,
      (float*)d_out);
}